// Round 8
// baseline (1120.407 us; speedup 1.0000x reference)
//
#include <hip/hip_runtime.h>
#include <stdint.h>
#include <math.h>

// ---------- types / helpers ----------
typedef _Float16 f16x8 __attribute__((ext_vector_type(8)));
typedef float    f32x4 __attribute__((ext_vector_type(4)));

__device__ __forceinline__ unsigned short f2h(float x) {
    _Float16 h = (_Float16)x;
    return __builtin_bit_cast(unsigned short, h);
}
__device__ __forceinline__ float h2f(unsigned short u) {
    return (float)__builtin_bit_cast(_Float16, u);
}

// B=2, S=2048, Hid=2048, NH=16, NKV=4, D=128, chunks: 8 x 256, TOPK=4
//
// Gate strategy (margin-filtered repair):
//  - exact fp64 kmean via rope-factorization (ksum/kmeanw)
//  - provisional gates from fp16-MFMA q vs exact km64; margin < TAU -> fp64 repair
// Value path: fp16 MFMA QKV GEMM, fp32 rope, fp16 MFMA flash attn
// (barrier-free main loop, K/V fragments direct from global), fp16 out-proj.

#define TAU 0.015

// ---------- CR-fp32 sincos tables ----------
__global__ void sctab_kernel(float* __restrict__ ct, float* __restrict__ st) {
    int gid = blockIdx.x * 256 + threadIdx.x;   // 2048*64
    int i = gid & 63, s = gid >> 6;
    float xf = (float)i * (1.0f / 64.0f);
    float pf = (float)pow(10000.0, (double)xf);     // CR fp32 pow
    float inv = 1.0f / pf;                          // second fp32 rounding (np)
    float ang = (float)s * inv;
    ct[gid] = (float)cos((double)ang);
    st[gid] = (float)sin((double)ang);
}

// ---------- trig-weighted chunk sums: Act/Ast[bn][h][d] (fp64) ----------
__global__ __launch_bounds__(256)
void ksum_kernel(const float* __restrict__ hs, const float* __restrict__ ct,
                 const float* __restrict__ st, double* __restrict__ Act,
                 double* __restrict__ Ast) {
    __shared__ float Hs[16][68];
    __shared__ float Tc[16][68];
    __shared__ float Ts[16][68];
    int bn = blockIdx.y;             // b*8 + n
    int h0 = blockIdx.x * 64;
    int b = bn >> 3, n = bn & 7;
    int t = threadIdx.x;
    int tx = t & 15, ty = t >> 4;
    int d0 = tx * 4, hl0 = ty * 4;
    int si = t & 15, g4 = (t >> 4) * 4;
    double ac[4][4] = {}, as_[4][4] = {};
    for (int s0 = 0; s0 < 256; s0 += 16) {
        __syncthreads();
        int srow = n * 256 + s0 + si;
        *(float4*)&Hs[si][g4] = *(const float4*)&hs[(size_t)(b * 2048 + srow) * 2048 + h0 + g4];
        *(float4*)&Tc[si][g4] = *(const float4*)&ct[srow * 64 + g4];
        *(float4*)&Ts[si][g4] = *(const float4*)&st[srow * 64 + g4];
        __syncthreads();
        #pragma unroll
        for (int kk = 0; kk < 16; ++kk) {
            double hv[4], cv[4], sv[4];
            #pragma unroll
            for (int j = 0; j < 4; ++j) hv[j] = (double)Hs[kk][hl0 + j];
            #pragma unroll
            for (int i = 0; i < 4; ++i) { cv[i] = (double)Tc[kk][d0 + i]; sv[i] = (double)Ts[kk][d0 + i]; }
            #pragma unroll
            for (int i = 0; i < 4; ++i)
                #pragma unroll
                for (int j = 0; j < 4; ++j) {
                    ac[i][j]  = fma(cv[i], hv[j], ac[i][j]);
                    as_[i][j] = fma(sv[i], hv[j], as_[i][j]);
                }
        }
    }
    #pragma unroll
    for (int j = 0; j < 4; ++j) {
        size_t rb = ((size_t)bn * 2048 + h0 + hl0 + j) * 64 + d0;
        double2 c0 = {ac[0][j], ac[1][j]},  c1 = {ac[2][j], ac[3][j]};
        double2 s0_ = {as_[0][j], as_[1][j]}, s1_ = {as_[2][j], as_[3][j]};
        *(double2*)&Act[rb] = c0; *(double2*)&Act[rb + 2] = c1;
        *(double2*)&Ast[rb] = s0_; *(double2*)&Ast[rb + 2] = s1_;
    }
}

// ---------- zero km64 ----------
__global__ void kmzero_kernel(double* __restrict__ km) {
    int i = blockIdx.x * 256 + threadIdx.x;
    if (i < 8192) km[i] = 0.0;
}

// ---------- contract Act/Ast with wk -> exact km64 ----------
__global__ __launch_bounds__(256)
void kmeanw_kernel(const double* __restrict__ Act, const double* __restrict__ Ast,
                   const float* __restrict__ wk, double* __restrict__ km) {
    __shared__ double red[256];
    int blk = blockIdx.x;            // (bn*4 + kvh)*4 + hp
    int hp = blk & 3, kvh = (blk >> 2) & 3, bn = blk >> 4;
    int t = threadIdx.x;
    int d = t & 127, sub = t >> 7;
    int jj = d & 63;
    int col1 = kvh * 128 + d;
    int col2 = kvh * 128 + (d ^ 64);
    double sgn = (d < 64) ? -1.0 : 1.0;
    const double* actb = Act + (size_t)bn * 2048 * 64;
    const double* astb = Ast + (size_t)bn * 2048 * 64;
    double acc1 = 0.0, acc2 = 0.0;
    int hbeg = hp * 512 + sub * 256;
    for (int h = hbeg; h < hbeg + 256; ++h) {
        acc1 = fma(actb[(size_t)h * 64 + jj], (double)wk[(size_t)h * 512 + col1], acc1);
        acc2 = fma(astb[(size_t)h * 64 + jj], (double)wk[(size_t)h * 512 + col2], acc2);
    }
    red[t] = acc1 + sgn * acc2;
    __syncthreads();
    if (t < 128) {
        double v = red[t] + red[t + 128];
        atomicAdd(&km[((size_t)bn * 4 + kvh) * 128 + d], v * (1.0 / 256.0));
    }
}

// ---------- zero the flag counter ----------
__global__ void zeroflag_kernel(int* __restrict__ flagcnt) {
    if (threadIdx.x == 0 && blockIdx.x == 0) *flagcnt = 0;
}

// ---------- provisional gates + margin flags ----------
__global__ void gatebase_kernel(const float* __restrict__ C, const double* __restrict__ km,
                                unsigned int* __restrict__ maskbuf,
                                int* __restrict__ flagcnt, int* __restrict__ flaglist) {
    int wid  = (blockIdx.x * 256 + threadIdx.x) >> 6;  // (b,h,s)
    int lane = threadIdx.x & 63;
    int s = wid & 2047;
    int h = (wid >> 11) & 15;
    int b = wid >> 15;
    int kvh = h >> 2;
    size_t qb = (size_t)(b * 2048 + s) * 3072 + h * 128;
    double q0 = (double)C[qb + lane], q1 = (double)C[qb + 64 + lane];
    double g[8];
    #pragma unroll
    for (int n = 0; n < 8; ++n) {
        size_t kb = (size_t)((b * 8 + n) * 4 + kvh) * 128;
        double v = q0 * km[kb + lane] + q1 * km[kb + 64 + lane];
        #pragma unroll
        for (int off = 32; off; off >>= 1) v += __shfl_xor(v, off);
        g[n] = v;
    }
    int qc = s >> 8;
    const double INF = __builtin_inf();
    #pragma unroll
    for (int n = 0; n < 8; ++n) {
        if (n == qc)                g[n] = INF;
        else if (s < (n + 1) * 256) g[n] = -INF;
    }
    unsigned int msk = 0;
    for (int p = 0; p < 4; ++p) {
        double best = -INF; int bi = -1;
        #pragma unroll
        for (int n = 0; n < 8; ++n)
            if (!((msk >> n) & 1) && g[n] > best) { best = g[n]; bi = n; }
        if (bi >= 0) msk |= 1u << bi;
    }
    if (lane == 0) {
        maskbuf[wid] = msk;
        if (qc >= 4) {
            double worst_in = INF, best_out = -INF;
            #pragma unroll
            for (int n = 0; n < 8; ++n) {
                if ((msk >> n) & 1) worst_in = fmin(worst_in, g[n]);
                else if (g[n] > -1e300) best_out = fmax(best_out, g[n]);
            }
            if (worst_in - best_out < TAU) {
                int ix = atomicAdd(flagcnt, 1);
                flaglist[ix] = wid;
            }
        }
    }
}

// ---------- exact fp64 repair of flagged queries ----------
__global__ __launch_bounds__(256)
void repair_kernel(const float* __restrict__ hs, const float* __restrict__ wq,
                   const float* __restrict__ ct, const float* __restrict__ st,
                   const double* __restrict__ km, const int* __restrict__ flagcnt,
                   const int* __restrict__ flaglist, unsigned int* __restrict__ maskbuf) {
    __shared__ double red[256];
    __shared__ double qs[128];
    int nflag = *flagcnt;
    int t = threadIdx.x;
    int d = t & 127, half = t >> 7;
    for (int idx = blockIdx.x; idx < nflag; idx += gridDim.x) {
        int wid = flaglist[idx];
        int s = wid & 2047;
        int h = (wid >> 11) & 15;
        int b = wid >> 15;
        int kvh = h >> 2;
        const float* hrow = hs + (size_t)(b * 2048 + s) * 2048 + half * 1024;
        const float* wcol = wq + (size_t)half * 1024 * 2048 + h * 128 + d;
        double acc = 0.0;
        #pragma unroll 4
        for (int k = 0; k < 1024; ++k)
            acc = fma((double)hrow[k], (double)wcol[(size_t)k * 2048], acc);
        red[t] = acc;
        __syncthreads();
        if (t < 128) qs[t] = red[t] + red[t + 128];
        __syncthreads();
        if (t < 64) {
            double c  = (double)ct[s * 64 + t];
            double sn = (double)st[s * 64 + t];
            double x1 = qs[t], x2 = qs[t + 64];
            qs[t]      = x1 * c - x2 * sn;
            qs[t + 64] = x2 * c + x1 * sn;
        }
        __syncthreads();
        if (t < 64) {
            double g[8];
            #pragma unroll
            for (int n = 0; n < 8; ++n) {
                size_t kb = (size_t)((b * 8 + n) * 4 + kvh) * 128;
                double v = qs[t] * km[kb + t] + qs[t + 64] * km[kb + 64 + t];
                #pragma unroll
                for (int off = 32; off; off >>= 1) v += __shfl_xor(v, off);
                g[n] = v;
            }
            int qc = s >> 8;
            const double INF = __builtin_inf();
            #pragma unroll
            for (int n = 0; n < 8; ++n) {
                if (n == qc)                g[n] = INF;
                else if (s < (n + 1) * 256) g[n] = -INF;
            }
            unsigned int msk = 0;
            for (int p = 0; p < 4; ++p) {
                double best = -INF; int bi = -1;
                #pragma unroll
                for (int n = 0; n < 8; ++n)
                    if (!((msk >> n) & 1) && g[n] > best) { best = g[n]; bi = n; }
                if (bi >= 0) msk |= 1u << bi;
            }
            if (t == 0) maskbuf[wid] = msk;
        }
        __syncthreads();
    }
}

// ================= fp16 value path =================

__global__ void split_kernel(const float* __restrict__ src,
                             unsigned short* __restrict__ hi, int n4) {
    int i = blockIdx.x * 256 + threadIdx.x;
    if (i >= n4) return;
    float4 v = ((const float4*)src)[i];
    ushort4 h;
    h.x = f2h(v.x); h.y = f2h(v.y); h.z = f2h(v.z); h.w = f2h(v.w);
    ((ushort4*)hi)[i] = h;
}

__global__ void packw_kernel(const float* __restrict__ wq, const float* __restrict__ wk,
                             const float* __restrict__ wv, unsigned short* __restrict__ Wh) {
    int gid = blockIdx.x * 256 + threadIdx.x;   // 3072 * 512
    int n  = gid % 3072;
    int kg = gid / 3072;
    const float* src; int ldn, col;
    if (n < 2048)      { src = wq; ldn = 2048; col = n; }
    else if (n < 2560) { src = wk; ldn = 512;  col = n - 2048; }
    else               { src = wv; ldn = 512;  col = n - 2560; }
    int k0 = kg * 4;
    ushort4 h;
    h.x = f2h(src[(size_t)(k0 + 0) * ldn + col]);
    h.y = f2h(src[(size_t)(k0 + 1) * ldn + col]);
    h.z = f2h(src[(size_t)(k0 + 2) * ldn + col]);
    h.w = f2h(src[(size_t)(k0 + 3) * ldn + col]);
    *(ushort4*)&Wh[(size_t)n * 2048 + k0] = h;
}

__global__ void packwo_kernel(const float* __restrict__ wo, unsigned short* __restrict__ Wh) {
    int gid = blockIdx.x * 256 + threadIdx.x;   // 2048 * 512
    int n  = gid % 2048;
    int kg = gid / 2048;
    int k0 = kg * 4;
    ushort4 h;
    h.x = f2h(wo[(size_t)(k0 + 0) * 2048 + n]);
    h.y = f2h(wo[(size_t)(k0 + 1) * 2048 + n]);
    h.z = f2h(wo[(size_t)(k0 + 2) * 2048 + n]);
    h.w = f2h(wo[(size_t)(k0 + 3) * 2048 + n]);
    *(ushort4*)&Wh[(size_t)n * 2048 + k0] = h;
}

__global__ __launch_bounds__(256, 2)
void gemm_kernel(const unsigned short* __restrict__ A_g, const unsigned short* __restrict__ B_g,
                 float* __restrict__ Cg, int M, int N, int K) {
    const int BK = 32;
    __shared__ unsigned short Ah[128][BK + 8];
    __shared__ unsigned short Bh[128][BK + 8];
    int n0 = blockIdx.x * 128, m0 = blockIdx.y * 128;
    int t = threadIdx.x;
    int wave = t >> 6, lane = t & 63;
    int quad = lane >> 4, l15 = lane & 15;
    int wm = (wave >> 1) * 64, wn = (wave & 1) * 64;

    f32x4 acc[4][4];
    f32x4 zero = {0.f, 0.f, 0.f, 0.f};
    for (int i = 0; i < 4; ++i)
        for (int j = 0; j < 4; ++j) acc[i][j] = zero;

    int srow = t >> 3;
    int scol = (t & 7) * 4;

    for (int k0 = 0; k0 < K; k0 += BK) {
        __syncthreads();
        #pragma unroll
        for (int it = 0; it < 4; ++it) {
            int r = srow + it * 32;
            *(ushort4*)&Ah[r][scol] = *(const ushort4*)&A_g[(size_t)(m0 + r) * K + k0 + scol];
            *(ushort4*)&Bh[r][scol] = *(const ushort4*)&B_g[(size_t)(n0 + r) * K + k0 + scol];
        }
        __syncthreads();
        f16x8 ah[4], bh[4];
        #pragma unroll
        for (int i = 0; i < 4; ++i) {
            ah[i] = *(const f16x8*)&Ah[wm + i * 16 + l15][quad * 8];
            bh[i] = *(const f16x8*)&Bh[wn + i * 16 + l15][quad * 8];
        }
        #pragma unroll
        for (int i = 0; i < 4; ++i)
            #pragma unroll
            for (int j = 0; j < 4; ++j)
                acc[i][j] = __builtin_amdgcn_mfma_f32_16x16x32_f16(ah[i], bh[j], acc[i][j], 0, 0, 0);
    }
    #pragma unroll
    for (int i = 0; i < 4; ++i)
        #pragma unroll
        for (int j = 0; j < 4; ++j)
            #pragma unroll
            for (int r = 0; r < 4; ++r) {
                int row = m0 + wm + i * 16 + quad * 4 + r;
                int col = n0 + wn + j * 16 + l15;
                Cg[(size_t)row * N + col] = acc[i][j][r];
            }
}

__global__ void rope_kernel(float* __restrict__ C, const float* __restrict__ ct,
                            const float* __restrict__ st) {
    int gid = blockIdx.x * 256 + threadIdx.x;   // 4096*20*64
    int i   = gid & 63;
    int rem = gid >> 6;
    int head = rem % 20;
    int m    = rem / 20;
    int s = m & 2047;
    float cs = ct[s * 64 + i], sn = st[s * 64 + i];
    size_t base = (size_t)m * 3072 + head * 128;
    float x1 = C[base + i], x2 = C[base + i + 64];
    C[base + i]      = x1 * cs - x2 * sn;
    C[base + i + 64] = x2 * cs + x1 * sn;
}

// ---------- kv prep: K -> fp16 row-major, V -> fp16 transposed ----------
__global__ void kvprep_kernel(const float* __restrict__ C, unsigned short* __restrict__ Kh,
                              unsigned short* __restrict__ Vt) {
    __shared__ unsigned short vt[128][72];
    int blk = blockIdx.x;          // (b*4+kvh)*32 + kt
    int kt = blk & 31, kvh = (blk >> 5) & 3, b = blk >> 7;
    int t = threadIdx.x;
    int key0 = kt * 64;
    #pragma unroll
    for (int it = 0; it < 8; ++it) {
        int idx = t + it * 256;
        int r = idx >> 5, c = (idx & 31) * 4;
        size_t rowb = (size_t)(b * 2048 + key0 + r) * 3072;
        float4 kv = *(const float4*)&C[rowb + 2048 + kvh * 128 + c];
        ushort4 u; u.x = f2h(kv.x); u.y = f2h(kv.y); u.z = f2h(kv.z); u.w = f2h(kv.w);
        *(ushort4*)&Kh[((size_t)(b * 4 + kvh) * 2048 + key0 + r) * 128 + c] = u;
        float4 vv = *(const float4*)&C[rowb + 2560 + kvh * 128 + c];
        vt[c + 0][r] = f2h(vv.x); vt[c + 1][r] = f2h(vv.y);
        vt[c + 2][r] = f2h(vv.z); vt[c + 3][r] = f2h(vv.w);
    }
    __syncthreads();
    #pragma unroll
    for (int it = 0; it < 8; ++it) {
        int idx = t + it * 256;
        int d = idx >> 4, c4 = (idx & 15) * 4;
        *(ushort4*)&Vt[((size_t)(b * 4 + kvh) * 128 + d) * 2048 + key0 + c4] =
            *(ushort4*)&vt[d][c4];
    }
}

// ---------- MFMA flash attention, barrier-free main loop ----------
// K/V MFMA B-fragments are loaded directly from global (16B/lane, L1/L2-hot);
// no per-subtile __syncthreads. p_s round-trip is wave-private. One barrier
// after Q staging, one before the coalesced output store.
__global__ __launch_bounds__(256, 3)
void attn_kernel(const float* __restrict__ C, const unsigned short* __restrict__ Kh,
                 const unsigned short* __restrict__ Vt,
                 const unsigned int* __restrict__ maskbuf,
                 unsigned short* __restrict__ Og) {
    __shared__ unsigned short q_s[64][136];   // q tile; reused for output
    __shared__ unsigned short p_s[64][68];    // stride 68: quads land on distinct bank groups
    int bid = blockIdx.x;                     // (b*16+h)*32 + qt
    int qt = bid & 31, h = (bid >> 5) & 15, b = bid >> 9;
    int t = threadIdx.x;
    int wave = t >> 6, lane = t & 63;
    int quad = lane >> 4, l15 = lane & 15;
    int w16 = wave * 16;
    int q0 = qt * 64, qc = q0 >> 8, kvh = h >> 2;
    const float NEGINF = -__builtin_inff();

    // stage Q (fp32 -> fp16)
    #pragma unroll
    for (int it = 0; it < 8; ++it) {
        int idx = t + it * 256;
        int r = idx >> 5, c = (idx & 31) * 4;
        float4 v4 = *(const float4*)&C[(size_t)(b * 2048 + q0 + r) * 3072 + h * 128 + c];
        ushort4 u; u.x = f2h(v4.x); u.y = f2h(v4.y); u.z = f2h(v4.z); u.w = f2h(v4.w);
        *(ushort4*)&q_s[r][c] = u;
    }
    int mbase = ((b * 16 + h) << 11) + q0;
    unsigned int am[4];
    #pragma unroll
    for (int r = 0; r < 4; ++r)
        am[r] = maskbuf[mbase + w16 + quad * 4 + r];
    // wave-level union of chunk masks (am is l15-invariant; union over quads)
    unsigned int um = am[0] | am[1] | am[2] | am[3];
    um |= (unsigned int)__shfl_xor((int)um, 16);
    um |= (unsigned int)__shfl_xor((int)um, 32);
    __syncthreads();
    // preload Q A-frags (own 16-row strip only)
    f16x8 aq[4];
    #pragma unroll
    for (int ks = 0; ks < 4; ++ks)
        aq[ks] = *(const f16x8*)&q_s[w16 + l15][ks * 32 + quad * 8];

    float m_i[4], l_i[4];
    f32x4 o_acc[8];
    #pragma unroll
    for (int r = 0; r < 4; ++r) { m_i[r] = NEGINF; l_i[r] = 0.f; }
    #pragma unroll
    for (int n = 0; n < 8; ++n) o_acc[n] = (f32x4){0.f, 0.f, 0.f, 0.f};
    const float scale = 0.08838834764831845f;
    const unsigned short* Kb = Kh + (size_t)(b * 4 + kvh) * 2048 * 128;
    const unsigned short* Vb = Vt + (size_t)(b * 4 + kvh) * 128 * 2048;

    for (int c = 0; c <= qc; ++c) {
        if (!((um >> c) & 1)) continue;
        int submax = (c == qc) ? ((q0 & 255) >> 6) : 3;
        for (int sub = 0; sub <= submax; ++sub) {
            int kbase = c * 256 + sub * 64;
            // S = Q K^T  (16q x 64k per wave); K B-frags direct from global
            f32x4 s[4];
            #pragma unroll
            for (int j = 0; j < 4; ++j) {
                const unsigned short* krow = Kb + (size_t)(kbase + j * 16 + l15) * 128 + quad * 8;
                f32x4 sj = {0.f, 0.f, 0.f, 0.f};
                #pragma unroll
                for (int ks = 0; ks < 4; ++ks) {
                    f16x8 bf = *(const f16x8*)(krow + ks * 32);
                    sj = __builtin_amdgcn_mfma_f32_16x16x32_f16(aq[ks], bf, sj, 0, 0, 0);
                }
                s[j] = sj;
            }
            // online softmax per row (row = quad*4 + r), wave-private
            #pragma unroll
            for (int r = 0; r < 4; ++r) {
                int qpos = q0 + w16 + quad * 4 + r;
                bool allow = (am[r] >> c) & 1;
                float sv[4], rmax = NEGINF;
                #pragma unroll
                for (int j = 0; j < 4; ++j) {
                    int kpos = kbase + j * 16 + l15;
                    float x = s[j][r] * scale;
                    if (!allow || kpos > qpos) x = NEGINF;
                    sv[j] = x;
                    rmax = fmaxf(rmax, x);
                }
                rmax = fmaxf(rmax, __shfl_xor(rmax, 1));
                rmax = fmaxf(rmax, __shfl_xor(rmax, 2));
                rmax = fmaxf(rmax, __shfl_xor(rmax, 4));
                rmax = fmaxf(rmax, __shfl_xor(rmax, 8));
                float mnew = fmaxf(m_i[r], rmax);
                float alpha = (m_i[r] == NEGINF) ? 0.f : __expf(m_i[r] - mnew);
                float ps[4], lsum = 0.f;
                #pragma unroll
                for (int j = 0; j < 4; ++j) {
                    float p = (sv[j] == NEGINF) ? 0.f : __expf(sv[j] - mnew);
                    ps[j] = p; lsum += p;
                }
                lsum += __shfl_xor(lsum, 1);
                lsum += __shfl_xor(lsum, 2);
                lsum += __shfl_xor(lsum, 4);
                lsum += __shfl_xor(lsum, 8);
                l_i[r] = l_i[r] * alpha + lsum;
                m_i[r] = mnew;
                #pragma unroll
                for (int n = 0; n < 8; ++n) o_acc[n][r] *= alpha;
                #pragma unroll
                for (int j = 0; j < 4; ++j)
                    p_s[w16 + quad * 4 + r][j * 16 + l15] = f2h(ps[j]);
            }
            // O += P V  (p via wave-private LDS round-trip; V B-frags direct global)
            f16x8 pa0 = *(const f16x8*)&p_s[w16 + l15][quad * 8];
            f16x8 pa1 = *(const f16x8*)&p_s[w16 + l15][32 + quad * 8];
            #pragma unroll
            for (int n = 0; n < 8; ++n) {
                const unsigned short* vrow = Vb + (size_t)(n * 16 + l15) * 2048 + kbase + quad * 8;
                f16x8 b0 = *(const f16x8*)(vrow);
                f16x8 b1 = *(const f16x8*)(vrow + 32);
                o_acc[n] = __builtin_amdgcn_mfma_f32_16x16x32_f16(pa0, b0, o_acc[n], 0, 0, 0);
                o_acc[n] = __builtin_amdgcn_mfma_f32_16x16x32_f16(pa1, b1, o_acc[n], 0, 0, 0);
            }
        }
    }
    // epilogue: normalize into own strip of q_s, then one barrier + coalesced store
    #pragma unroll
    for (int r = 0; r < 4; ++r) {
        float inv = (l_i[r] > 0.f) ? 1.f / l_i[r] : 0.f;
        #pragma unroll
        for (int n = 0; n < 8; ++n)
            q_s[w16 + quad * 4 + r][n * 16 + l15] = f2h(o_acc[n][r] * inv);
    }
    __syncthreads();
    #pragma unroll
    for (int it = 0; it < 8; ++it) {
        int idx = t + it * 256;
        int r = idx >> 5, cpos = (idx & 31) * 4;
        *(ushort4*)&Og[(size_t)(b * 2048 + q0 + r) * 2048 + h * 128 + cpos] =
            *(ushort4*)&q_s[r][cpos];
    }
}

// ---------- launch ----------
extern "C" void kernel_launch(void* const* d_in, const int* in_sizes, int n_in,
                              void* d_out, int out_size, void* d_ws, size_t ws_size,
                              hipStream_t stream) {
    const float* hs = (const float*)d_in[0];
    const float* wq = (const float*)d_in[1];
    const float* wk = (const float*)d_in[2];
    const float* wv = (const float*)d_in[3];
    const float* wo = (const float*)d_in[4];
    float* out = (float*)d_out;
    char* ws = (char*)d_ws;

    // phase-1 (gate) buffers, overlapped with the Cqkv region:
    double*         Act  = (double*)       (ws + 37748736);    // 16.78 MB
    double*         Ast  = (double*)       (ws + 54525952);    // 16.78 MB
    // phase-2 buffers:
    unsigned short* hsh  = (unsigned short*)(ws + 0);          // 16.78 MB
    unsigned short* Wth  = (unsigned short*)(ws + 16777216);   // 12.58 MB
    unsigned short* woth = (unsigned short*)(ws + 29360128);   //  8.39 MB
    float*          Cqkv = (float*)        (ws + 37748736);    // 50.33 MB
    unsigned short* Og   = (unsigned short*)(ws + 88080384);   // 16.78 MB
    // persistent:
    double*         km64 = (double*)       (ws + 104857600);   // 64 KB
    unsigned int*   mskb = (unsigned int*) (ws + 104923136);   // 512 KB
    float*          ct   = (float*)        (ws + 105447424);   // 512 KB
    float*          st   = (float*)        (ws + 105971712);   // 512 KB
    unsigned short* Kh   = (unsigned short*)(ws + 106496000);  //  8.39 MB
    unsigned short* Vt   = (unsigned short*)(ws + 114884608);  //  8.39 MB
    int*            fcnt = (int*)          (ws + 123273216);   // 64 B
    int*            flst = (int*)          (ws + 123273280);   // 256 KB

    // phase 1: exact km64 via rope-factorized trig-weighted sums
    sctab_kernel  <<<512, 256, 0, stream>>>(ct, st);
    ksum_kernel   <<<dim3(32, 16), 256, 0, stream>>>(hs, ct, st, Act, Ast);
    kmzero_kernel <<<32, 256, 0, stream>>>(km64);
    kmeanw_kernel <<<256, 256, 0, stream>>>(Act, Ast, wk, km64);
    // phase 2: fp16 value path (also feeds provisional gates)
    split_kernel  <<<8192, 256, 0, stream>>>(hs, hsh, 2097152);
    packw_kernel  <<<6144, 256, 0, stream>>>(wq, wk, wv, Wth);
    packwo_kernel <<<4096, 256, 0, stream>>>(wo, woth);
    gemm_kernel   <<<dim3(24, 32), 256, 0, stream>>>(hsh, Wth, Cqkv, 4096, 3072, 2048);
    rope_kernel   <<<20480, 256, 0, stream>>>(Cqkv, ct, st);
    // gates: provisional + margin-filtered exact repair
    zeroflag_kernel<<<1, 64, 0, stream>>>(fcnt);
    gatebase_kernel<<<16384, 256, 0, stream>>>(Cqkv, km64, mskb, fcnt, flst);
    repair_kernel <<<2048, 256, 0, stream>>>(hs, wq, ct, st, km64, fcnt, flst, mskb);
    // attention + out-proj
    kvprep_kernel <<<256, 256, 0, stream>>>(Cqkv, Kh, Vt);
    attn_kernel   <<<1024, 256, 0, stream>>>(Cqkv, Kh, Vt, mskb, Og);
    gemm_kernel   <<<dim3(16, 32), 256, 0, stream>>>(Og, woth, out, 4096, 2048, 2048);
}

// Round 9
// 736.536 us; speedup vs baseline: 1.5212x; 1.5212x over previous
//
#include <hip/hip_runtime.h>
#include <stdint.h>
#include <math.h>

// ---------- types / helpers ----------
typedef _Float16 f16x8 __attribute__((ext_vector_type(8)));
typedef float    f32x4 __attribute__((ext_vector_type(4)));

__device__ __forceinline__ unsigned short f2h(float x) {
    _Float16 h = (_Float16)x;
    return __builtin_bit_cast(unsigned short, h);
}
__device__ __forceinline__ float h2f(unsigned short u) {
    return (float)__builtin_bit_cast(_Float16, u);
}

// B=2, S=2048, Hid=2048, NH=16, NKV=4, D=128, chunks: 8 x 256, TOPK=4
//
// Gate strategy (margin-filtered repair):
//  - exact fp64 kmean via rope-factorization (ksum/kmeanw)
//  - provisional gates from fp16-MFMA q vs exact km64; margin < TAU -> fp64 repair
// Value path: fp16 MFMA QKV GEMM, fp32 rope, fp16 MFMA flash attention with
// LDS-staged K/V + register-prefetch pipeline (R8 showed direct-global
// fragments are latency-bound), fp16 out-proj.

#define TAU 0.015

// ---------- CR-fp32 sincos tables ----------
__global__ void sctab_kernel(float* __restrict__ ct, float* __restrict__ st) {
    int gid = blockIdx.x * 256 + threadIdx.x;   // 2048*64
    int i = gid & 63, s = gid >> 6;
    float xf = (float)i * (1.0f / 64.0f);
    float pf = (float)pow(10000.0, (double)xf);     // CR fp32 pow
    float inv = 1.0f / pf;                          // second fp32 rounding (np)
    float ang = (float)s * inv;
    ct[gid] = (float)cos((double)ang);
    st[gid] = (float)sin((double)ang);
}

// ---------- trig-weighted chunk sums: Act/Ast[bn][h][d] (fp64) ----------
__global__ __launch_bounds__(256)
void ksum_kernel(const float* __restrict__ hs, const float* __restrict__ ct,
                 const float* __restrict__ st, double* __restrict__ Act,
                 double* __restrict__ Ast) {
    __shared__ float Hs[16][68];
    __shared__ float Tc[16][68];
    __shared__ float Ts[16][68];
    int bn = blockIdx.y;             // b*8 + n
    int h0 = blockIdx.x * 64;
    int b = bn >> 3, n = bn & 7;
    int t = threadIdx.x;
    int tx = t & 15, ty = t >> 4;
    int d0 = tx * 4, hl0 = ty * 4;
    int si = t & 15, g4 = (t >> 4) * 4;
    double ac[4][4] = {}, as_[4][4] = {};
    for (int s0 = 0; s0 < 256; s0 += 16) {
        __syncthreads();
        int srow = n * 256 + s0 + si;
        *(float4*)&Hs[si][g4] = *(const float4*)&hs[(size_t)(b * 2048 + srow) * 2048 + h0 + g4];
        *(float4*)&Tc[si][g4] = *(const float4*)&ct[srow * 64 + g4];
        *(float4*)&Ts[si][g4] = *(const float4*)&st[srow * 64 + g4];
        __syncthreads();
        #pragma unroll
        for (int kk = 0; kk < 16; ++kk) {
            double hv[4], cv[4], sv[4];
            #pragma unroll
            for (int j = 0; j < 4; ++j) hv[j] = (double)Hs[kk][hl0 + j];
            #pragma unroll
            for (int i = 0; i < 4; ++i) { cv[i] = (double)Tc[kk][d0 + i]; sv[i] = (double)Ts[kk][d0 + i]; }
            #pragma unroll
            for (int i = 0; i < 4; ++i)
                #pragma unroll
                for (int j = 0; j < 4; ++j) {
                    ac[i][j]  = fma(cv[i], hv[j], ac[i][j]);
                    as_[i][j] = fma(sv[i], hv[j], as_[i][j]);
                }
        }
    }
    #pragma unroll
    for (int j = 0; j < 4; ++j) {
        size_t rb = ((size_t)bn * 2048 + h0 + hl0 + j) * 64 + d0;
        double2 c0 = {ac[0][j], ac[1][j]},  c1 = {ac[2][j], ac[3][j]};
        double2 s0_ = {as_[0][j], as_[1][j]}, s1_ = {as_[2][j], as_[3][j]};
        *(double2*)&Act[rb] = c0; *(double2*)&Act[rb + 2] = c1;
        *(double2*)&Ast[rb] = s0_; *(double2*)&Ast[rb + 2] = s1_;
    }
}

// ---------- zero km64 ----------
__global__ void kmzero_kernel(double* __restrict__ km) {
    int i = blockIdx.x * 256 + threadIdx.x;
    if (i < 8192) km[i] = 0.0;
}

// ---------- contract Act/Ast with wk -> exact km64 ----------
__global__ __launch_bounds__(256)
void kmeanw_kernel(const double* __restrict__ Act, const double* __restrict__ Ast,
                   const float* __restrict__ wk, double* __restrict__ km) {
    __shared__ double red[256];
    int blk = blockIdx.x;            // (bn*4 + kvh)*4 + hp
    int hp = blk & 3, kvh = (blk >> 2) & 3, bn = blk >> 4;
    int t = threadIdx.x;
    int d = t & 127, sub = t >> 7;
    int jj = d & 63;
    int col1 = kvh * 128 + d;
    int col2 = kvh * 128 + (d ^ 64);
    double sgn = (d < 64) ? -1.0 : 1.0;
    const double* actb = Act + (size_t)bn * 2048 * 64;
    const double* astb = Ast + (size_t)bn * 2048 * 64;
    double acc1 = 0.0, acc2 = 0.0;
    int hbeg = hp * 512 + sub * 256;
    for (int h = hbeg; h < hbeg + 256; ++h) {
        acc1 = fma(actb[(size_t)h * 64 + jj], (double)wk[(size_t)h * 512 + col1], acc1);
        acc2 = fma(astb[(size_t)h * 64 + jj], (double)wk[(size_t)h * 512 + col2], acc2);
    }
    red[t] = acc1 + sgn * acc2;
    __syncthreads();
    if (t < 128) {
        double v = red[t] + red[t + 128];
        atomicAdd(&km[((size_t)bn * 4 + kvh) * 128 + d], v * (1.0 / 256.0));
    }
}

// ---------- zero the flag counter ----------
__global__ void zeroflag_kernel(int* __restrict__ flagcnt) {
    if (threadIdx.x == 0 && blockIdx.x == 0) *flagcnt = 0;
}

// ---------- provisional gates + margin flags ----------
__global__ void gatebase_kernel(const float* __restrict__ C, const double* __restrict__ km,
                                unsigned int* __restrict__ maskbuf,
                                int* __restrict__ flagcnt, int* __restrict__ flaglist) {
    int wid  = (blockIdx.x * 256 + threadIdx.x) >> 6;  // (b,h,s)
    int lane = threadIdx.x & 63;
    int s = wid & 2047;
    int h = (wid >> 11) & 15;
    int b = wid >> 15;
    int kvh = h >> 2;
    size_t qb = (size_t)(b * 2048 + s) * 3072 + h * 128;
    double q0 = (double)C[qb + lane], q1 = (double)C[qb + 64 + lane];
    double g[8];
    #pragma unroll
    for (int n = 0; n < 8; ++n) {
        size_t kb = (size_t)((b * 8 + n) * 4 + kvh) * 128;
        double v = q0 * km[kb + lane] + q1 * km[kb + 64 + lane];
        #pragma unroll
        for (int off = 32; off; off >>= 1) v += __shfl_xor(v, off);
        g[n] = v;
    }
    int qc = s >> 8;
    const double INF = __builtin_inf();
    #pragma unroll
    for (int n = 0; n < 8; ++n) {
        if (n == qc)                g[n] = INF;
        else if (s < (n + 1) * 256) g[n] = -INF;
    }
    unsigned int msk = 0;
    for (int p = 0; p < 4; ++p) {
        double best = -INF; int bi = -1;
        #pragma unroll
        for (int n = 0; n < 8; ++n)
            if (!((msk >> n) & 1) && g[n] > best) { best = g[n]; bi = n; }
        if (bi >= 0) msk |= 1u << bi;
    }
    if (lane == 0) {
        maskbuf[wid] = msk;
        if (qc >= 4) {
            double worst_in = INF, best_out = -INF;
            #pragma unroll
            for (int n = 0; n < 8; ++n) {
                if ((msk >> n) & 1) worst_in = fmin(worst_in, g[n]);
                else if (g[n] > -1e300) best_out = fmax(best_out, g[n]);
            }
            if (worst_in - best_out < TAU) {
                int ix = atomicAdd(flagcnt, 1);
                flaglist[ix] = wid;
            }
        }
    }
}

// ---------- exact fp64 repair of flagged queries ----------
__global__ __launch_bounds__(256)
void repair_kernel(const float* __restrict__ hs, const float* __restrict__ wq,
                   const float* __restrict__ ct, const float* __restrict__ st,
                   const double* __restrict__ km, const int* __restrict__ flagcnt,
                   const int* __restrict__ flaglist, unsigned int* __restrict__ maskbuf) {
    __shared__ double red[256];
    __shared__ double qs[128];
    int nflag = *flagcnt;
    int t = threadIdx.x;
    int d = t & 127, half = t >> 7;
    for (int idx = blockIdx.x; idx < nflag; idx += gridDim.x) {
        int wid = flaglist[idx];
        int s = wid & 2047;
        int h = (wid >> 11) & 15;
        int b = wid >> 15;
        int kvh = h >> 2;
        const float* hrow = hs + (size_t)(b * 2048 + s) * 2048 + half * 1024;
        const float* wcol = wq + (size_t)half * 1024 * 2048 + h * 128 + d;
        double acc = 0.0;
        #pragma unroll 4
        for (int k = 0; k < 1024; ++k)
            acc = fma((double)hrow[k], (double)wcol[(size_t)k * 2048], acc);
        red[t] = acc;
        __syncthreads();
        if (t < 128) qs[t] = red[t] + red[t + 128];
        __syncthreads();
        if (t < 64) {
            double c  = (double)ct[s * 64 + t];
            double sn = (double)st[s * 64 + t];
            double x1 = qs[t], x2 = qs[t + 64];
            qs[t]      = x1 * c - x2 * sn;
            qs[t + 64] = x2 * c + x1 * sn;
        }
        __syncthreads();
        if (t < 64) {
            double g[8];
            #pragma unroll
            for (int n = 0; n < 8; ++n) {
                size_t kb = (size_t)((b * 8 + n) * 4 + kvh) * 128;
                double v = qs[t] * km[kb + t] + qs[t + 64] * km[kb + 64 + t];
                #pragma unroll
                for (int off = 32; off; off >>= 1) v += __shfl_xor(v, off);
                g[n] = v;
            }
            int qc = s >> 8;
            const double INF = __builtin_inf();
            #pragma unroll
            for (int n = 0; n < 8; ++n) {
                if (n == qc)                g[n] = INF;
                else if (s < (n + 1) * 256) g[n] = -INF;
            }
            unsigned int msk = 0;
            for (int p = 0; p < 4; ++p) {
                double best = -INF; int bi = -1;
                #pragma unroll
                for (int n = 0; n < 8; ++n)
                    if (!((msk >> n) & 1) && g[n] > best) { best = g[n]; bi = n; }
                if (bi >= 0) msk |= 1u << bi;
            }
            if (t == 0) maskbuf[wid] = msk;
        }
        __syncthreads();
    }
}

// ================= fp16 value path =================

__global__ void split_kernel(const float* __restrict__ src,
                             unsigned short* __restrict__ hi, int n4) {
    int i = blockIdx.x * 256 + threadIdx.x;
    if (i >= n4) return;
    float4 v = ((const float4*)src)[i];
    ushort4 h;
    h.x = f2h(v.x); h.y = f2h(v.y); h.z = f2h(v.z); h.w = f2h(v.w);
    ((ushort4*)hi)[i] = h;
}

__global__ void packw_kernel(const float* __restrict__ wq, const float* __restrict__ wk,
                             const float* __restrict__ wv, unsigned short* __restrict__ Wh) {
    int gid = blockIdx.x * 256 + threadIdx.x;   // 3072 * 512
    int n  = gid % 3072;
    int kg = gid / 3072;
    const float* src; int ldn, col;
    if (n < 2048)      { src = wq; ldn = 2048; col = n; }
    else if (n < 2560) { src = wk; ldn = 512;  col = n - 2048; }
    else               { src = wv; ldn = 512;  col = n - 2560; }
    int k0 = kg * 4;
    ushort4 h;
    h.x = f2h(src[(size_t)(k0 + 0) * ldn + col]);
    h.y = f2h(src[(size_t)(k0 + 1) * ldn + col]);
    h.z = f2h(src[(size_t)(k0 + 2) * ldn + col]);
    h.w = f2h(src[(size_t)(k0 + 3) * ldn + col]);
    *(ushort4*)&Wh[(size_t)n * 2048 + k0] = h;
}

__global__ void packwo_kernel(const float* __restrict__ wo, unsigned short* __restrict__ Wh) {
    int gid = blockIdx.x * 256 + threadIdx.x;   // 2048 * 512
    int n  = gid % 2048;
    int kg = gid / 2048;
    int k0 = kg * 4;
    ushort4 h;
    h.x = f2h(wo[(size_t)(k0 + 0) * 2048 + n]);
    h.y = f2h(wo[(size_t)(k0 + 1) * 2048 + n]);
    h.z = f2h(wo[(size_t)(k0 + 2) * 2048 + n]);
    h.w = f2h(wo[(size_t)(k0 + 3) * 2048 + n]);
    *(ushort4*)&Wh[(size_t)n * 2048 + k0] = h;
}

__global__ __launch_bounds__(256, 2)
void gemm_kernel(const unsigned short* __restrict__ A_g, const unsigned short* __restrict__ B_g,
                 float* __restrict__ Cg, int M, int N, int K) {
    const int BK = 32;
    __shared__ unsigned short Ah[128][BK + 8];
    __shared__ unsigned short Bh[128][BK + 8];
    int n0 = blockIdx.x * 128, m0 = blockIdx.y * 128;
    int t = threadIdx.x;
    int wave = t >> 6, lane = t & 63;
    int quad = lane >> 4, l15 = lane & 15;
    int wm = (wave >> 1) * 64, wn = (wave & 1) * 64;

    f32x4 acc[4][4];
    f32x4 zero = {0.f, 0.f, 0.f, 0.f};
    for (int i = 0; i < 4; ++i)
        for (int j = 0; j < 4; ++j) acc[i][j] = zero;

    int srow = t >> 3;
    int scol = (t & 7) * 4;

    for (int k0 = 0; k0 < K; k0 += BK) {
        __syncthreads();
        #pragma unroll
        for (int it = 0; it < 4; ++it) {
            int r = srow + it * 32;
            *(ushort4*)&Ah[r][scol] = *(const ushort4*)&A_g[(size_t)(m0 + r) * K + k0 + scol];
            *(ushort4*)&Bh[r][scol] = *(const ushort4*)&B_g[(size_t)(n0 + r) * K + k0 + scol];
        }
        __syncthreads();
        f16x8 ah[4], bh[4];
        #pragma unroll
        for (int i = 0; i < 4; ++i) {
            ah[i] = *(const f16x8*)&Ah[wm + i * 16 + l15][quad * 8];
            bh[i] = *(const f16x8*)&Bh[wn + i * 16 + l15][quad * 8];
        }
        #pragma unroll
        for (int i = 0; i < 4; ++i)
            #pragma unroll
            for (int j = 0; j < 4; ++j)
                acc[i][j] = __builtin_amdgcn_mfma_f32_16x16x32_f16(ah[i], bh[j], acc[i][j], 0, 0, 0);
    }
    #pragma unroll
    for (int i = 0; i < 4; ++i)
        #pragma unroll
        for (int j = 0; j < 4; ++j)
            #pragma unroll
            for (int r = 0; r < 4; ++r) {
                int row = m0 + wm + i * 16 + quad * 4 + r;
                int col = n0 + wn + j * 16 + l15;
                Cg[(size_t)row * N + col] = acc[i][j][r];
            }
}

__global__ void rope_kernel(float* __restrict__ C, const float* __restrict__ ct,
                            const float* __restrict__ st) {
    int gid = blockIdx.x * 256 + threadIdx.x;   // 4096*20*64
    int i   = gid & 63;
    int rem = gid >> 6;
    int head = rem % 20;
    int m    = rem / 20;
    int s = m & 2047;
    float cs = ct[s * 64 + i], sn = st[s * 64 + i];
    size_t base = (size_t)m * 3072 + head * 128;
    float x1 = C[base + i], x2 = C[base + i + 64];
    C[base + i]      = x1 * cs - x2 * sn;
    C[base + i + 64] = x2 * cs + x1 * sn;
}

// ---------- kv prep: K -> fp16 row-major, V -> fp16 transposed ----------
__global__ void kvprep_kernel(const float* __restrict__ C, unsigned short* __restrict__ Kh,
                              unsigned short* __restrict__ Vt) {
    __shared__ unsigned short vt[128][72];
    int blk = blockIdx.x;          // (b*4+kvh)*32 + kt
    int kt = blk & 31, kvh = (blk >> 5) & 3, b = blk >> 7;
    int t = threadIdx.x;
    int key0 = kt * 64;
    #pragma unroll
    for (int it = 0; it < 8; ++it) {
        int idx = t + it * 256;
        int r = idx >> 5, c = (idx & 31) * 4;
        size_t rowb = (size_t)(b * 2048 + key0 + r) * 3072;
        float4 kv = *(const float4*)&C[rowb + 2048 + kvh * 128 + c];
        ushort4 u; u.x = f2h(kv.x); u.y = f2h(kv.y); u.z = f2h(kv.z); u.w = f2h(kv.w);
        *(ushort4*)&Kh[((size_t)(b * 4 + kvh) * 2048 + key0 + r) * 128 + c] = u;
        float4 vv = *(const float4*)&C[rowb + 2560 + kvh * 128 + c];
        vt[c + 0][r] = f2h(vv.x); vt[c + 1][r] = f2h(vv.y);
        vt[c + 2][r] = f2h(vv.z); vt[c + 3][r] = f2h(vv.w);
    }
    __syncthreads();
    #pragma unroll
    for (int it = 0; it < 8; ++it) {
        int idx = t + it * 256;
        int d = idx >> 4, c4 = (idx & 15) * 4;
        *(ushort4*)&Vt[((size_t)(b * 4 + kvh) * 128 + d) * 2048 + key0 + c4] =
            *(ushort4*)&vt[d][c4];
    }
}

// ---------- MFMA flash attention: LDS-staged, register-prefetch pipelined ----------
// Per block: (b, h, 64-query tile); 4 waves x 16-query strips.
// K/V for subtile i+1 prefetched into VGPRs during subtile i's compute; the
// two per-subtile barriers bracket only cheap reg->LDS writes.
// LDS 43 KB (V-tile aliases dead Q staging; output aliases K tile) -> 3 blk/CU.
// Heavy q-tiles scheduled first (qt descending in blockIdx).
__global__ __launch_bounds__(256, 3)
void attn_kernel(const float* __restrict__ C, const unsigned short* __restrict__ Kh,
                 const unsigned short* __restrict__ Vt,
                 const unsigned int* __restrict__ maskbuf,
                 unsigned short* __restrict__ Og) {
    __shared__ unsigned short qv[8704];   // Q [64][132] -> V^T [128][68]
    __shared__ unsigned short k_s[8448];  // K [64][132]; output staging at end
    __shared__ unsigned short p_s[4352];  // P [64][68]
    __shared__ int kb_list[32];
    __shared__ int nsub_s;
    __shared__ unsigned int umask;

    int bid = blockIdx.x;
    int qt = 31 - (bid >> 5);             // longest-work-first
    int bh = bid & 31;
    int h = bh & 15, b = bh >> 4;
    int t = threadIdx.x;
    int wave = t >> 6, lane = t & 63;
    int quad = lane >> 4, l15 = lane & 15;
    int w16 = wave * 16;
    int q0 = qt * 64, qc = q0 >> 8, kvh = h >> 2;
    const float NEGINF = -__builtin_inff();

    // stage Q (fp32 -> fp16) into qv as [64][132]
    #pragma unroll
    for (int it = 0; it < 8; ++it) {
        int idx = t + it * 256;
        int r = idx >> 5, c = (idx & 31) * 4;
        float4 v4 = *(const float4*)&C[(size_t)(b * 2048 + q0 + r) * 3072 + h * 128 + c];
        ushort4 u; u.x = f2h(v4.x); u.y = f2h(v4.y); u.z = f2h(v4.z); u.w = f2h(v4.w);
        *(ushort4*)&qv[r * 132 + c] = u;
    }
    if (t == 0) umask = 0;
    int mbase = ((b * 16 + h) << 11) + q0;
    unsigned int am[4];
    #pragma unroll
    for (int r = 0; r < 4; ++r)
        am[r] = maskbuf[mbase + w16 + quad * 4 + r];
    __syncthreads();                       // Q staged; umask init
    if (t < 64) atomicOr(&umask, maskbuf[mbase + t]);
    f16x8 aq[4];
    #pragma unroll
    for (int ks = 0; ks < 4; ++ks)
        aq[ks] = *(const f16x8*)&qv[(w16 + l15) * 132 + ks * 32 + quad * 8];
    __syncthreads();                       // umask final; aq loaded
    if (t == 0) {                          // build subtile list (block-uniform)
        unsigned int um = umask;
        int n = 0;
        for (int c = 0; c <= qc; ++c) {
            if (!((um >> c) & 1)) continue;
            int submax = (c == qc) ? ((q0 & 255) >> 6) : 3;
            for (int sub = 0; sub <= submax; ++sub) kb_list[n++] = c * 256 + sub * 64;
        }
        nsub_s = n;
    }
    __syncthreads();                       // list ready
    int nsub = nsub_s;

    float m_i[4], l_i[4];
    f32x4 o_acc[8];
    #pragma unroll
    for (int r = 0; r < 4; ++r) { m_i[r] = NEGINF; l_i[r] = 0.f; }
    #pragma unroll
    for (int n = 0; n < 8; ++n) o_acc[n] = (f32x4){0.f, 0.f, 0.f, 0.f};
    const float scale = 0.08838834764831845f;
    const unsigned short* Kb = Kh + (size_t)(b * 4 + kvh) * 2048 * 128;
    const unsigned short* Vb = Vt + (size_t)(b * 4 + kvh) * 128 * 2048;

    // staging thread mapping
    int kr = t >> 5, kc = (t & 31) * 4;    // K: rows kr, kr+8..; dims kc..kc+3
    int vr = t >> 4, vc = (t & 15) * 4;    // V: dims vr, vr+16..; keys vc..vc+3

    // prefetch subtile 0
    ushort4 kpre[8], vpre[8];
    {
        int kb0 = kb_list[0];
        #pragma unroll
        for (int it = 0; it < 8; ++it) {
            kpre[it] = *(const ushort4*)&Kb[(size_t)(kb0 + kr + it * 8) * 128 + kc];
            vpre[it] = *(const ushort4*)&Vb[(size_t)(vr + it * 16) * 2048 + kb0 + vc];
        }
    }

    for (int i = 0; i < nsub; ++i) {
        int kbase = kb_list[i];
        __syncthreads();                   // prior compute done; safe to overwrite LDS
        #pragma unroll
        for (int it = 0; it < 8; ++it) {
            *(ushort4*)&k_s[(kr + it * 8) * 132 + kc] = kpre[it];
            *(ushort4*)&qv[(vr + it * 16) * 68 + vc] = vpre[it];
        }
        __syncthreads();                   // staging visible
        if (i + 1 < nsub) {                // prefetch next subtile during compute
            int kbn = kb_list[i + 1];
            #pragma unroll
            for (int it = 0; it < 8; ++it) {
                kpre[it] = *(const ushort4*)&Kb[(size_t)(kbn + kr + it * 8) * 128 + kc];
                vpre[it] = *(const ushort4*)&Vb[(size_t)(vr + it * 16) * 2048 + kbn + vc];
            }
        }
        // S = Q K^T  (16q x 64k per wave)
        f32x4 s[4];
        #pragma unroll
        for (int j = 0; j < 4; ++j) {
            f32x4 sj = {0.f, 0.f, 0.f, 0.f};
            #pragma unroll
            for (int ks = 0; ks < 4; ++ks) {
                f16x8 bf = *(const f16x8*)&k_s[(j * 16 + l15) * 132 + ks * 32 + quad * 8];
                sj = __builtin_amdgcn_mfma_f32_16x16x32_f16(aq[ks], bf, sj, 0, 0, 0);
            }
            s[j] = sj;
        }
        // online softmax per row (row = quad*4 + r), wave-private
        #pragma unroll
        for (int r = 0; r < 4; ++r) {
            int qpos = q0 + w16 + quad * 4 + r;
            bool allow = (am[r] >> (kbase >> 8)) & 1;
            float sv[4], rmax = NEGINF;
            #pragma unroll
            for (int j = 0; j < 4; ++j) {
                int kpos = kbase + j * 16 + l15;
                float x = s[j][r] * scale;
                if (!allow || kpos > qpos) x = NEGINF;
                sv[j] = x;
                rmax = fmaxf(rmax, x);
            }
            rmax = fmaxf(rmax, __shfl_xor(rmax, 1));
            rmax = fmaxf(rmax, __shfl_xor(rmax, 2));
            rmax = fmaxf(rmax, __shfl_xor(rmax, 4));
            rmax = fmaxf(rmax, __shfl_xor(rmax, 8));
            float mnew = fmaxf(m_i[r], rmax);
            float alpha = (m_i[r] == NEGINF) ? 0.f : __expf(m_i[r] - mnew);
            float ps[4], lsum = 0.f;
            #pragma unroll
            for (int j = 0; j < 4; ++j) {
                float p = (sv[j] == NEGINF) ? 0.f : __expf(sv[j] - mnew);
                ps[j] = p; lsum += p;
            }
            lsum += __shfl_xor(lsum, 1);
            lsum += __shfl_xor(lsum, 2);
            lsum += __shfl_xor(lsum, 4);
            lsum += __shfl_xor(lsum, 8);
            l_i[r] = l_i[r] * alpha + lsum;
            m_i[r] = mnew;
            #pragma unroll
            for (int n = 0; n < 8; ++n) o_acc[n][r] *= alpha;
            #pragma unroll
            for (int j = 0; j < 4; ++j)
                p_s[(w16 + quad * 4 + r) * 68 + j * 16 + l15] = f2h(ps[j]);
        }
        // O += P V  (p_s round-trip is wave-private; V from LDS)
        f16x8 pa0 = *(const f16x8*)&p_s[(w16 + l15) * 68 + quad * 8];
        f16x8 pa1 = *(const f16x8*)&p_s[(w16 + l15) * 68 + 32 + quad * 8];
        #pragma unroll
        for (int n = 0; n < 8; ++n) {
            f16x8 b0 = *(const f16x8*)&qv[(n * 16 + l15) * 68 + quad * 8];
            f16x8 b1 = *(const f16x8*)&qv[(n * 16 + l15) * 68 + 32 + quad * 8];
            o_acc[n] = __builtin_amdgcn_mfma_f32_16x16x32_f16(pa0, b0, o_acc[n], 0, 0, 0);
            o_acc[n] = __builtin_amdgcn_mfma_f32_16x16x32_f16(pa1, b1, o_acc[n], 0, 0, 0);
        }
    }
    // epilogue: normalize into k_s (dead), one barrier, coalesced store
    __syncthreads();
    #pragma unroll
    for (int r = 0; r < 4; ++r) {
        float inv = (l_i[r] > 0.f) ? 1.f / l_i[r] : 0.f;
        #pragma unroll
        for (int n = 0; n < 8; ++n)
            k_s[(w16 + quad * 4 + r) * 132 + n * 16 + l15] = f2h(o_acc[n][r] * inv);
    }
    __syncthreads();
    #pragma unroll
    for (int it = 0; it < 8; ++it) {
        int idx = t + it * 256;
        int r = idx >> 5, cpos = (idx & 31) * 4;
        *(ushort4*)&Og[(size_t)(b * 2048 + q0 + r) * 2048 + h * 128 + cpos] =
            *(ushort4*)&k_s[r * 132 + cpos];
    }
}

// ---------- launch ----------
extern "C" void kernel_launch(void* const* d_in, const int* in_sizes, int n_in,
                              void* d_out, int out_size, void* d_ws, size_t ws_size,
                              hipStream_t stream) {
    const float* hs = (const float*)d_in[0];
    const float* wq = (const float*)d_in[1];
    const float* wk = (const float*)d_in[2];
    const float* wv = (const float*)d_in[3];
    const float* wo = (const float*)d_in[4];
    float* out = (float*)d_out;
    char* ws = (char*)d_ws;

    // phase-1 (gate) buffers, overlapped with the Cqkv region:
    double*         Act  = (double*)       (ws + 37748736);    // 16.78 MB
    double*         Ast  = (double*)       (ws + 54525952);    // 16.78 MB
    // phase-2 buffers:
    unsigned short* hsh  = (unsigned short*)(ws + 0);          // 16.78 MB
    unsigned short* Wth  = (unsigned short*)(ws + 16777216);   // 12.58 MB
    unsigned short* woth = (unsigned short*)(ws + 29360128);   //  8.39 MB
    float*          Cqkv = (float*)        (ws + 37748736);    // 50.33 MB
    unsigned short* Og   = (unsigned short*)(ws + 88080384);   // 16.78 MB
    // persistent:
    double*         km64 = (double*)       (ws + 104857600);   // 64 KB
    unsigned int*   mskb = (unsigned int*) (ws + 104923136);   // 512 KB
    float*          ct   = (float*)        (ws + 105447424);   // 512 KB
    float*          st   = (float*)        (ws + 105971712);   // 512 KB
    unsigned short* Kh   = (unsigned short*)(ws + 106496000);  //  8.39 MB
    unsigned short* Vt   = (unsigned short*)(ws + 114884608);  //  8.39 MB
    int*            fcnt = (int*)          (ws + 123273216);   // 64 B
    int*            flst = (int*)          (ws + 123273280);   // 256 KB

    // phase 1: exact km64 via rope-factorized trig-weighted sums
    sctab_kernel  <<<512, 256, 0, stream>>>(ct, st);
    ksum_kernel   <<<dim3(32, 16), 256, 0, stream>>>(hs, ct, st, Act, Ast);
    kmzero_kernel <<<32, 256, 0, stream>>>(km64);
    kmeanw_kernel <<<256, 256, 0, stream>>>(Act, Ast, wk, km64);
    // phase 2: fp16 value path (also feeds provisional gates)
    split_kernel  <<<8192, 256, 0, stream>>>(hs, hsh, 2097152);
    packw_kernel  <<<6144, 256, 0, stream>>>(wq, wk, wv, Wth);
    packwo_kernel <<<4096, 256, 0, stream>>>(wo, woth);
    gemm_kernel   <<<dim3(24, 32), 256, 0, stream>>>(hsh, Wth, Cqkv, 4096, 3072, 2048);
    rope_kernel   <<<20480, 256, 0, stream>>>(Cqkv, ct, st);
    // gates: provisional + margin-filtered exact repair
    zeroflag_kernel<<<1, 64, 0, stream>>>(fcnt);
    gatebase_kernel<<<16384, 256, 0, stream>>>(Cqkv, km64, mskb, fcnt, flst);
    repair_kernel <<<2048, 256, 0, stream>>>(hs, wq, ct, st, km64, fcnt, flst, mskb);
    // attention + out-proj
    kvprep_kernel <<<256, 256, 0, stream>>>(Cqkv, Kh, Vt);
    attn_kernel   <<<1024, 256, 0, stream>>>(Cqkv, Kh, Vt, mskb, Og);
    gemm_kernel   <<<dim3(16, 32), 256, 0, stream>>>(Og, woth, out, 4096, 2048, 2048);
}

// Round 10
// 713.668 us; speedup vs baseline: 1.5699x; 1.0320x over previous
//
#include <hip/hip_runtime.h>
#include <stdint.h>
#include <math.h>

// ---------- types / helpers ----------
typedef _Float16 f16x8 __attribute__((ext_vector_type(8)));
typedef float    f32x4 __attribute__((ext_vector_type(4)));
typedef __attribute__((address_space(1))) void as1_void;
typedef __attribute__((address_space(3))) void as3_void;

__device__ __forceinline__ unsigned short f2h(float x) {
    _Float16 h = (_Float16)x;
    return __builtin_bit_cast(unsigned short, h);
}
__device__ __forceinline__ float h2f(unsigned short u) {
    return (float)__builtin_bit_cast(_Float16, u);
}
// async global->LDS, 16B/lane; lds dest must be wave-uniform base (HW adds lane*16)
__device__ __forceinline__ void glds16(const void* g, void* l) {
    __builtin_amdgcn_global_load_lds((as1_void*)g, (as3_void*)l, 16, 0, 0);
}

// B=2, S=2048, Hid=2048, NH=16, NKV=4, D=128, chunks: 8 x 256, TOPK=4
//
// Gate strategy (margin-filtered repair):
//  - exact fp64 kmean via rope-factorization (ksum/kmeanw)
//  - provisional gates from fp16-MFMA q vs exact km64 (fused into ropegate);
//    margin < TAU -> exact fp64 repair of that query
// Value path: fp16 MFMA QKV GEMM (global_load_lds staging), fused fp32
// rope+gates, fp16 MFMA flash attn (LDS-staged + register prefetch), fp16 out-proj.

#define TAU 0.015

// ---------- setup: CR-fp32 sincos tables + zero km64 + zero flag counter ----------
__global__ void setup_kernel(float* __restrict__ ct, float* __restrict__ st,
                             double* __restrict__ km, int* __restrict__ flagcnt) {
    int gid = blockIdx.x * 256 + threadIdx.x;   // 512*256 = 2048*64
    if (gid == 0) *flagcnt = 0;
    if (gid < 8192) km[gid] = 0.0;
    int i = gid & 63, s = gid >> 6;
    float xf = (float)i * (1.0f / 64.0f);
    float pf = (float)pow(10000.0, (double)xf);     // CR fp32 pow
    float inv = 1.0f / pf;                          // second fp32 rounding (np)
    float ang = (float)s * inv;
    ct[gid] = (float)cos((double)ang);
    st[gid] = (float)sin((double)ang);
}

// ---------- trig-weighted chunk sums: Act/Ast[bn][h][d] (fp64) ----------
__global__ __launch_bounds__(256)
void ksum_kernel(const float* __restrict__ hs, const float* __restrict__ ct,
                 const float* __restrict__ st, double* __restrict__ Act,
                 double* __restrict__ Ast) {
    __shared__ float Hs[16][68];
    __shared__ float Tc[16][68];
    __shared__ float Ts[16][68];
    int bn = blockIdx.y;             // b*8 + n
    int h0 = blockIdx.x * 64;
    int b = bn >> 3, n = bn & 7;
    int t = threadIdx.x;
    int tx = t & 15, ty = t >> 4;
    int d0 = tx * 4, hl0 = ty * 4;
    int si = t & 15, g4 = (t >> 4) * 4;
    double ac[4][4] = {}, as_[4][4] = {};
    for (int s0 = 0; s0 < 256; s0 += 16) {
        __syncthreads();
        int srow = n * 256 + s0 + si;
        *(float4*)&Hs[si][g4] = *(const float4*)&hs[(size_t)(b * 2048 + srow) * 2048 + h0 + g4];
        *(float4*)&Tc[si][g4] = *(const float4*)&ct[srow * 64 + g4];
        *(float4*)&Ts[si][g4] = *(const float4*)&st[srow * 64 + g4];
        __syncthreads();
        #pragma unroll
        for (int kk = 0; kk < 16; ++kk) {
            double hv[4], cv[4], sv[4];
            #pragma unroll
            for (int j = 0; j < 4; ++j) hv[j] = (double)Hs[kk][hl0 + j];
            #pragma unroll
            for (int i = 0; i < 4; ++i) { cv[i] = (double)Tc[kk][d0 + i]; sv[i] = (double)Ts[kk][d0 + i]; }
            #pragma unroll
            for (int i = 0; i < 4; ++i)
                #pragma unroll
                for (int j = 0; j < 4; ++j) {
                    ac[i][j]  = fma(cv[i], hv[j], ac[i][j]);
                    as_[i][j] = fma(sv[i], hv[j], as_[i][j]);
                }
        }
    }
    #pragma unroll
    for (int j = 0; j < 4; ++j) {
        size_t rb = ((size_t)bn * 2048 + h0 + hl0 + j) * 64 + d0;
        double2 c0 = {ac[0][j], ac[1][j]},  c1 = {ac[2][j], ac[3][j]};
        double2 s0_ = {as_[0][j], as_[1][j]}, s1_ = {as_[2][j], as_[3][j]};
        *(double2*)&Act[rb] = c0; *(double2*)&Act[rb + 2] = c1;
        *(double2*)&Ast[rb] = s0_; *(double2*)&Ast[rb + 2] = s1_;
    }
}

// ---------- contract Act/Ast with wk -> exact km64 ----------
__global__ __launch_bounds__(256)
void kmeanw_kernel(const double* __restrict__ Act, const double* __restrict__ Ast,
                   const float* __restrict__ wk, double* __restrict__ km) {
    __shared__ double red[256];
    int blk = blockIdx.x;            // (bn*4 + kvh)*4 + hp
    int hp = blk & 3, kvh = (blk >> 2) & 3, bn = blk >> 4;
    int t = threadIdx.x;
    int d = t & 127, sub = t >> 7;
    int jj = d & 63;
    int col1 = kvh * 128 + d;
    int col2 = kvh * 128 + (d ^ 64);
    double sgn = (d < 64) ? -1.0 : 1.0;
    const double* actb = Act + (size_t)bn * 2048 * 64;
    const double* astb = Ast + (size_t)bn * 2048 * 64;
    double acc1 = 0.0, acc2 = 0.0;
    int hbeg = hp * 512 + sub * 256;
    for (int h = hbeg; h < hbeg + 256; ++h) {
        acc1 = fma(actb[(size_t)h * 64 + jj], (double)wk[(size_t)h * 512 + col1], acc1);
        acc2 = fma(astb[(size_t)h * 64 + jj], (double)wk[(size_t)h * 512 + col2], acc2);
    }
    red[t] = acc1 + sgn * acc2;
    __syncthreads();
    if (t < 128) {
        double v = red[t] + red[t + 128];
        atomicAdd(&km[((size_t)bn * 4 + kvh) * 128 + d], v * (1.0 / 256.0));
    }
}

// ---------- fused rope (q,k in-place) + provisional fp64 gates + margin flags ----------
__global__ __launch_bounds__(256)
void ropegate_kernel(float* __restrict__ C, const float* __restrict__ ct,
                     const float* __restrict__ st, const double* __restrict__ km,
                     unsigned int* __restrict__ maskbuf,
                     int* __restrict__ flagcnt, int* __restrict__ flaglist) {
    __shared__ float qbuf[2048];
    int bs = blockIdx.x;             // b*2048 + s
    int s = bs & 2047, b = bs >> 11;
    int t = threadIdx.x;
    size_t base = (size_t)bs * 3072;
    #pragma unroll
    for (int it = 0; it < 5; ++it) {  // 20 heads x 64 pairs = 1280 = 5*256
        int p = t + it * 256;
        int hd = p >> 6, i = p & 63;
        float cs = ct[s * 64 + i], sn = st[s * 64 + i];
        float x1 = C[base + hd * 128 + i];
        float x2 = C[base + hd * 128 + i + 64];
        float n1 = x1 * cs - x2 * sn;
        float n2 = x2 * cs + x1 * sn;
        C[base + hd * 128 + i] = n1;
        C[base + hd * 128 + i + 64] = n2;
        if (hd < 16) { qbuf[hd * 128 + i] = n1; qbuf[hd * 128 + i + 64] = n2; }
    }
    __syncthreads();
    int wave = t >> 6, lane = t & 63;
    int qc = s >> 8;
    const double INF = __builtin_inf();
    #pragma unroll
    for (int ii = 0; ii < 4; ++ii) {
        int h = wave * 4 + ii;
        int kvh = h >> 2;
        double q0 = (double)qbuf[h * 128 + lane];
        double q1 = (double)qbuf[h * 128 + 64 + lane];
        double g[8];
        #pragma unroll
        for (int n = 0; n < 8; ++n) {
            size_t kb = (size_t)((b * 8 + n) * 4 + kvh) * 128;
            double v = q0 * km[kb + lane] + q1 * km[kb + 64 + lane];
            #pragma unroll
            for (int off = 32; off; off >>= 1) v += __shfl_xor(v, off);
            g[n] = v;
        }
        #pragma unroll
        for (int n = 0; n < 8; ++n) {
            if (n == qc)                g[n] = INF;
            else if (s < (n + 1) * 256) g[n] = -INF;
        }
        unsigned int msk = 0;
        for (int p = 0; p < 4; ++p) {  // iterative argmax; strict > => lowest idx on ties
            double best = -INF; int bi = -1;
            #pragma unroll
            for (int n = 0; n < 8; ++n)
                if (!((msk >> n) & 1) && g[n] > best) { best = g[n]; bi = n; }
            if (bi >= 0) msk |= 1u << bi;
        }
        if (lane == 0) {
            int wid = ((b * 16 + h) << 11) + s;
            maskbuf[wid] = msk;
            if (qc >= 4) {
                double worst_in = INF, best_out = -INF;
                #pragma unroll
                for (int n = 0; n < 8; ++n) {
                    if ((msk >> n) & 1) worst_in = fmin(worst_in, g[n]);
                    else if (g[n] > -1e300) best_out = fmax(best_out, g[n]);
                }
                if (worst_in - best_out < TAU) {
                    int ix = atomicAdd(flagcnt, 1);
                    flaglist[ix] = wid;
                }
            }
        }
    }
}

// ---------- exact fp64 repair of flagged queries ----------
__global__ __launch_bounds__(256)
void repair_kernel(const float* __restrict__ hs, const float* __restrict__ wq,
                   const float* __restrict__ ct, const float* __restrict__ st,
                   const double* __restrict__ km, const int* __restrict__ flagcnt,
                   const int* __restrict__ flaglist, unsigned int* __restrict__ maskbuf) {
    __shared__ double red[256];
    __shared__ double qs[128];
    int nflag = *flagcnt;
    int t = threadIdx.x;
    int d = t & 127, half = t >> 7;
    for (int idx = blockIdx.x; idx < nflag; idx += gridDim.x) {
        int wid = flaglist[idx];
        int s = wid & 2047;
        int h = (wid >> 11) & 15;
        int b = wid >> 15;
        int kvh = h >> 2;
        const float* hrow = hs + (size_t)(b * 2048 + s) * 2048 + half * 1024;
        const float* wcol = wq + (size_t)half * 1024 * 2048 + h * 128 + d;
        double acc = 0.0;
        #pragma unroll 4
        for (int k = 0; k < 1024; ++k)
            acc = fma((double)hrow[k], (double)wcol[(size_t)k * 2048], acc);
        red[t] = acc;
        __syncthreads();
        if (t < 128) qs[t] = red[t] + red[t + 128];
        __syncthreads();
        if (t < 64) {
            double c  = (double)ct[s * 64 + t];
            double sn = (double)st[s * 64 + t];
            double x1 = qs[t], x2 = qs[t + 64];
            qs[t]      = x1 * c - x2 * sn;
            qs[t + 64] = x2 * c + x1 * sn;
        }
        __syncthreads();
        if (t < 64) {
            double g[8];
            #pragma unroll
            for (int n = 0; n < 8; ++n) {
                size_t kb = (size_t)((b * 8 + n) * 4 + kvh) * 128;
                double v = qs[t] * km[kb + t] + qs[t + 64] * km[kb + 64 + t];
                #pragma unroll
                for (int off = 32; off; off >>= 1) v += __shfl_xor(v, off);
                g[n] = v;
            }
            int qc = s >> 8;
            const double INF = __builtin_inf();
            #pragma unroll
            for (int n = 0; n < 8; ++n) {
                if (n == qc)                g[n] = INF;
                else if (s < (n + 1) * 256) g[n] = -INF;
            }
            unsigned int msk = 0;
            for (int p = 0; p < 4; ++p) {
                double best = -INF; int bi = -1;
                #pragma unroll
                for (int n = 0; n < 8; ++n)
                    if (!((msk >> n) & 1) && g[n] > best) { best = g[n]; bi = n; }
                if (bi >= 0) msk |= 1u << bi;
            }
            if (t == 0) maskbuf[wid] = msk;
        }
        __syncthreads();
    }
}

// ================= fp16 value path =================

__global__ void split_kernel(const float* __restrict__ src,
                             unsigned short* __restrict__ hi, int n4) {
    int i = blockIdx.x * 256 + threadIdx.x;
    if (i >= n4) return;
    float4 v = ((const float4*)src)[i];
    ushort4 h;
    h.x = f2h(v.x); h.y = f2h(v.y); h.z = f2h(v.z); h.w = f2h(v.w);
    ((ushort4*)hi)[i] = h;
}

// ---------- pack [wq|wk|wv]^T -> Wh[n][k]  and  wo^T -> Woh[n][k], fp16 ----------
__global__ void packall_kernel(const float* __restrict__ wq, const float* __restrict__ wk,
                               const float* __restrict__ wv, const float* __restrict__ wo,
                               unsigned short* __restrict__ Wh, unsigned short* __restrict__ Woh) {
    int gid = blockIdx.x * 256 + threadIdx.x;
    if (gid < 3072 * 512) {
        int n  = gid % 3072;
        int kg = gid / 3072;
        const float* src; int ldn, col;
        if (n < 2048)      { src = wq; ldn = 2048; col = n; }
        else if (n < 2560) { src = wk; ldn = 512;  col = n - 2048; }
        else               { src = wv; ldn = 512;  col = n - 2560; }
        int k0 = kg * 4;
        ushort4 h;
        h.x = f2h(src[(size_t)(k0 + 0) * ldn + col]);
        h.y = f2h(src[(size_t)(k0 + 1) * ldn + col]);
        h.z = f2h(src[(size_t)(k0 + 2) * ldn + col]);
        h.w = f2h(src[(size_t)(k0 + 3) * ldn + col]);
        *(ushort4*)&Wh[(size_t)n * 2048 + k0] = h;
    } else {
        int g2 = gid - 3072 * 512;   // 2048*512
        int n  = g2 % 2048;
        int kg = g2 / 2048;
        int k0 = kg * 4;
        ushort4 h;
        h.x = f2h(wo[(size_t)(k0 + 0) * 2048 + n]);
        h.y = f2h(wo[(size_t)(k0 + 1) * 2048 + n]);
        h.z = f2h(wo[(size_t)(k0 + 2) * 2048 + n]);
        h.w = f2h(wo[(size_t)(k0 + 3) * 2048 + n]);
        *(ushort4*)&Woh[(size_t)n * 2048 + k0] = h;
    }
}

// ---------- fp16 MFMA GEMM, m97-style global_load_lds staging ----------
// A row-major [m][k]; B pre-transposed [n][k]; unpadded LDS tiles [128][32].
__global__ __launch_bounds__(256, 2)
void gemm_kernel(const unsigned short* __restrict__ A_g, const unsigned short* __restrict__ B_g,
                 float* __restrict__ Cg, int M, int N, int K) {
    __shared__ unsigned short Ah[128 * 32];
    __shared__ unsigned short Bh[128 * 32];
    int n0 = blockIdx.x * 128, m0 = blockIdx.y * 128;
    int t = threadIdx.x;
    int wave = t >> 6, lane = t & 63;
    int quad = lane >> 4, l15 = lane & 15;
    int wm = (wave >> 1) * 64, wn = (wave & 1) * 64;

    f32x4 acc[4][4];
    f32x4 zero = {0.f, 0.f, 0.f, 0.f};
    for (int i = 0; i < 4; ++i)
        for (int j = 0; j < 4; ++j) acc[i][j] = zero;

    // staging: lane covers row (lane>>2), 8 halves at col (lane&3)*8 of a 16-row segment
    int srow = lane >> 2, scol = (lane & 3) * 8;
    const unsigned short* Ag0 = &A_g[(size_t)(m0 + wave * 16 + srow) * K + scol];
    const unsigned short* Ag1 = &A_g[(size_t)(m0 + 64 + wave * 16 + srow) * K + scol];
    const unsigned short* Bg0 = &B_g[(size_t)(n0 + wave * 16 + srow) * K + scol];
    const unsigned short* Bg1 = &B_g[(size_t)(n0 + 64 + wave * 16 + srow) * K + scol];
    unsigned short* Al0 = &Ah[(wave * 16) * 32];
    unsigned short* Al1 = &Ah[(64 + wave * 16) * 32];
    unsigned short* Bl0 = &Bh[(wave * 16) * 32];
    unsigned short* Bl1 = &Bh[(64 + wave * 16) * 32];

    for (int k0 = 0; k0 < K; k0 += 32) {
        __syncthreads();
        glds16(Ag0 + k0, Al0);
        glds16(Ag1 + k0, Al1);
        glds16(Bg0 + k0, Bl0);
        glds16(Bg1 + k0, Bl1);
        __syncthreads();   // drains vmcnt -> staging visible
        f16x8 ah[4], bh[4];
        #pragma unroll
        for (int i = 0; i < 4; ++i) {
            ah[i] = *(const f16x8*)&Ah[(wm + i * 16 + l15) * 32 + quad * 8];
            bh[i] = *(const f16x8*)&Bh[(wn + i * 16 + l15) * 32 + quad * 8];
        }
        #pragma unroll
        for (int i = 0; i < 4; ++i)
            #pragma unroll
            for (int j = 0; j < 4; ++j)
                acc[i][j] = __builtin_amdgcn_mfma_f32_16x16x32_f16(ah[i], bh[j], acc[i][j], 0, 0, 0);
    }
    #pragma unroll
    for (int i = 0; i < 4; ++i)
        #pragma unroll
        for (int j = 0; j < 4; ++j)
            #pragma unroll
            for (int r = 0; r < 4; ++r) {
                int row = m0 + wm + i * 16 + quad * 4 + r;
                int col = n0 + wn + j * 16 + l15;
                Cg[(size_t)row * N + col] = acc[i][j][r];
            }
}

// ---------- kv prep: K -> fp16 row-major, V -> fp16 transposed ----------
__global__ void kvprep_kernel(const float* __restrict__ C, unsigned short* __restrict__ Kh,
                              unsigned short* __restrict__ Vt) {
    __shared__ unsigned short vt[128][72];
    int blk = blockIdx.x;          // (b*4+kvh)*32 + kt
    int kt = blk & 31, kvh = (blk >> 5) & 3, b = blk >> 7;
    int t = threadIdx.x;
    int key0 = kt * 64;
    #pragma unroll
    for (int it = 0; it < 8; ++it) {
        int idx = t + it * 256;
        int r = idx >> 5, c = (idx & 31) * 4;
        size_t rowb = (size_t)(b * 2048 + key0 + r) * 3072;
        float4 kv = *(const float4*)&C[rowb + 2048 + kvh * 128 + c];
        ushort4 u; u.x = f2h(kv.x); u.y = f2h(kv.y); u.z = f2h(kv.z); u.w = f2h(kv.w);
        *(ushort4*)&Kh[((size_t)(b * 4 + kvh) * 2048 + key0 + r) * 128 + c] = u;
        float4 vv = *(const float4*)&C[rowb + 2560 + kvh * 128 + c];
        vt[c + 0][r] = f2h(vv.x); vt[c + 1][r] = f2h(vv.y);
        vt[c + 2][r] = f2h(vv.z); vt[c + 3][r] = f2h(vv.w);
    }
    __syncthreads();
    #pragma unroll
    for (int it = 0; it < 8; ++it) {
        int idx = t + it * 256;
        int d = idx >> 4, c4 = (idx & 15) * 4;
        *(ushort4*)&Vt[((size_t)(b * 4 + kvh) * 128 + d) * 2048 + key0 + c4] =
            *(ushort4*)&vt[d][c4];
    }
}

// ---------- MFMA flash attention: LDS-staged, register-prefetch pipelined ----------
__global__ __launch_bounds__(256, 3)
void attn_kernel(const float* __restrict__ C, const unsigned short* __restrict__ Kh,
                 const unsigned short* __restrict__ Vt,
                 const unsigned int* __restrict__ maskbuf,
                 unsigned short* __restrict__ Og) {
    __shared__ unsigned short qv[8704];   // Q [64][132] -> V^T [128][68]
    __shared__ unsigned short k_s[8448];  // K [64][132]; output staging at end
    __shared__ unsigned short p_s[4352];  // P [64][68]
    __shared__ int kb_list[32];
    __shared__ int nsub_s;
    __shared__ unsigned int umask;

    int bid = blockIdx.x;
    int qt = 31 - (bid >> 5);             // longest-work-first
    int bh = bid & 31;
    int h = bh & 15, b = bh >> 4;
    int t = threadIdx.x;
    int wave = t >> 6, lane = t & 63;
    int quad = lane >> 4, l15 = lane & 15;
    int w16 = wave * 16;
    int q0 = qt * 64, qc = q0 >> 8, kvh = h >> 2;
    const float NEGINF = -__builtin_inff();

    #pragma unroll
    for (int it = 0; it < 8; ++it) {
        int idx = t + it * 256;
        int r = idx >> 5, c = (idx & 31) * 4;
        float4 v4 = *(const float4*)&C[(size_t)(b * 2048 + q0 + r) * 3072 + h * 128 + c];
        ushort4 u; u.x = f2h(v4.x); u.y = f2h(v4.y); u.z = f2h(v4.z); u.w = f2h(v4.w);
        *(ushort4*)&qv[r * 132 + c] = u;
    }
    if (t == 0) umask = 0;
    int mbase = ((b * 16 + h) << 11) + q0;
    unsigned int am[4];
    #pragma unroll
    for (int r = 0; r < 4; ++r)
        am[r] = maskbuf[mbase + w16 + quad * 4 + r];
    __syncthreads();
    if (t < 64) atomicOr(&umask, maskbuf[mbase + t]);
    f16x8 aq[4];
    #pragma unroll
    for (int ks = 0; ks < 4; ++ks)
        aq[ks] = *(const f16x8*)&qv[(w16 + l15) * 132 + ks * 32 + quad * 8];
    __syncthreads();
    if (t == 0) {
        unsigned int um = umask;
        int n = 0;
        for (int c = 0; c <= qc; ++c) {
            if (!((um >> c) & 1)) continue;
            int submax = (c == qc) ? ((q0 & 255) >> 6) : 3;
            for (int sub = 0; sub <= submax; ++sub) kb_list[n++] = c * 256 + sub * 64;
        }
        nsub_s = n;
    }
    __syncthreads();
    int nsub = nsub_s;

    float m_i[4], l_i[4];
    f32x4 o_acc[8];
    #pragma unroll
    for (int r = 0; r < 4; ++r) { m_i[r] = NEGINF; l_i[r] = 0.f; }
    #pragma unroll
    for (int n = 0; n < 8; ++n) o_acc[n] = (f32x4){0.f, 0.f, 0.f, 0.f};
    const float scale = 0.08838834764831845f;
    const unsigned short* Kb = Kh + (size_t)(b * 4 + kvh) * 2048 * 128;
    const unsigned short* Vb = Vt + (size_t)(b * 4 + kvh) * 128 * 2048;

    int kr = t >> 5, kc = (t & 31) * 4;
    int vr = t >> 4, vc = (t & 15) * 4;

    ushort4 kpre[8], vpre[8];
    {
        int kb0 = kb_list[0];
        #pragma unroll
        for (int it = 0; it < 8; ++it) {
            kpre[it] = *(const ushort4*)&Kb[(size_t)(kb0 + kr + it * 8) * 128 + kc];
            vpre[it] = *(const ushort4*)&Vb[(size_t)(vr + it * 16) * 2048 + kb0 + vc];
        }
    }

    for (int i = 0; i < nsub; ++i) {
        int kbase = kb_list[i];
        __syncthreads();
        #pragma unroll
        for (int it = 0; it < 8; ++it) {
            *(ushort4*)&k_s[(kr + it * 8) * 132 + kc] = kpre[it];
            *(ushort4*)&qv[(vr + it * 16) * 68 + vc] = vpre[it];
        }
        __syncthreads();
        if (i + 1 < nsub) {
            int kbn = kb_list[i + 1];
            #pragma unroll
            for (int it = 0; it < 8; ++it) {
                kpre[it] = *(const ushort4*)&Kb[(size_t)(kbn + kr + it * 8) * 128 + kc];
                vpre[it] = *(const ushort4*)&Vb[(size_t)(vr + it * 16) * 2048 + kbn + vc];
            }
        }
        f32x4 s[4];
        #pragma unroll
        for (int j = 0; j < 4; ++j) {
            f32x4 sj = {0.f, 0.f, 0.f, 0.f};
            #pragma unroll
            for (int ks = 0; ks < 4; ++ks) {
                f16x8 bf = *(const f16x8*)&k_s[(j * 16 + l15) * 132 + ks * 32 + quad * 8];
                sj = __builtin_amdgcn_mfma_f32_16x16x32_f16(aq[ks], bf, sj, 0, 0, 0);
            }
            s[j] = sj;
        }
        #pragma unroll
        for (int r = 0; r < 4; ++r) {
            int qpos = q0 + w16 + quad * 4 + r;
            bool allow = (am[r] >> (kbase >> 8)) & 1;
            float sv[4], rmax = NEGINF;
            #pragma unroll
            for (int j = 0; j < 4; ++j) {
                int kpos = kbase + j * 16 + l15;
                float x = s[j][r] * scale;
                if (!allow || kpos > qpos) x = NEGINF;
                sv[j] = x;
                rmax = fmaxf(rmax, x);
            }
            rmax = fmaxf(rmax, __shfl_xor(rmax, 1));
            rmax = fmaxf(rmax, __shfl_xor(rmax, 2));
            rmax = fmaxf(rmax, __shfl_xor(rmax, 4));
            rmax = fmaxf(rmax, __shfl_xor(rmax, 8));
            float mnew = fmaxf(m_i[r], rmax);
            float alpha = (m_i[r] == NEGINF) ? 0.f : __expf(m_i[r] - mnew);
            float ps[4], lsum = 0.f;
            #pragma unroll
            for (int j = 0; j < 4; ++j) {
                float p = (sv[j] == NEGINF) ? 0.f : __expf(sv[j] - mnew);
                ps[j] = p; lsum += p;
            }
            lsum += __shfl_xor(lsum, 1);
            lsum += __shfl_xor(lsum, 2);
            lsum += __shfl_xor(lsum, 4);
            lsum += __shfl_xor(lsum, 8);
            l_i[r] = l_i[r] * alpha + lsum;
            m_i[r] = mnew;
            #pragma unroll
            for (int n = 0; n < 8; ++n) o_acc[n][r] *= alpha;
            #pragma unroll
            for (int j = 0; j < 4; ++j)
                p_s[(w16 + quad * 4 + r) * 68 + j * 16 + l15] = f2h(ps[j]);
        }
        f16x8 pa0 = *(const f16x8*)&p_s[(w16 + l15) * 68 + quad * 8];
        f16x8 pa1 = *(const f16x8*)&p_s[(w16 + l15) * 68 + 32 + quad * 8];
        #pragma unroll
        for (int n = 0; n < 8; ++n) {
            f16x8 b0 = *(const f16x8*)&qv[(n * 16 + l15) * 68 + quad * 8];
            f16x8 b1 = *(const f16x8*)&qv[(n * 16 + l15) * 68 + 32 + quad * 8];
            o_acc[n] = __builtin_amdgcn_mfma_f32_16x16x32_f16(pa0, b0, o_acc[n], 0, 0, 0);
            o_acc[n] = __builtin_amdgcn_mfma_f32_16x16x32_f16(pa1, b1, o_acc[n], 0, 0, 0);
        }
    }
    __syncthreads();
    #pragma unroll
    for (int r = 0; r < 4; ++r) {
        float inv = (l_i[r] > 0.f) ? 1.f / l_i[r] : 0.f;
        #pragma unroll
        for (int n = 0; n < 8; ++n)
            k_s[(w16 + quad * 4 + r) * 132 + n * 16 + l15] = f2h(o_acc[n][r] * inv);
    }
    __syncthreads();
    #pragma unroll
    for (int it = 0; it < 8; ++it) {
        int idx = t + it * 256;
        int r = idx >> 5, cpos = (idx & 31) * 4;
        *(ushort4*)&Og[(size_t)(b * 2048 + q0 + r) * 2048 + h * 128 + cpos] =
            *(ushort4*)&k_s[r * 132 + cpos];
    }
}

// ---------- launch ----------
extern "C" void kernel_launch(void* const* d_in, const int* in_sizes, int n_in,
                              void* d_out, int out_size, void* d_ws, size_t ws_size,
                              hipStream_t stream) {
    const float* hs = (const float*)d_in[0];
    const float* wq = (const float*)d_in[1];
    const float* wk = (const float*)d_in[2];
    const float* wv = (const float*)d_in[3];
    const float* wo = (const float*)d_in[4];
    float* out = (float*)d_out;
    char* ws = (char*)d_ws;

    // phase-1 (gate) buffers, overlapped with the Cqkv region:
    double*         Act  = (double*)       (ws + 37748736);    // 16.78 MB
    double*         Ast  = (double*)       (ws + 54525952);    // 16.78 MB
    // phase-2 buffers:
    unsigned short* hsh  = (unsigned short*)(ws + 0);          // 16.78 MB
    unsigned short* Wth  = (unsigned short*)(ws + 16777216);   // 12.58 MB
    unsigned short* woth = (unsigned short*)(ws + 29360128);   //  8.39 MB
    float*          Cqkv = (float*)        (ws + 37748736);    // 50.33 MB
    unsigned short* Og   = (unsigned short*)(ws + 88080384);   // 16.78 MB
    // persistent:
    double*         km64 = (double*)       (ws + 104857600);   // 64 KB
    unsigned int*   mskb = (unsigned int*) (ws + 104923136);   // 512 KB
    float*          ct   = (float*)        (ws + 105447424);   // 512 KB
    float*          st   = (float*)        (ws + 105971712);   // 512 KB
    unsigned short* Kh   = (unsigned short*)(ws + 106496000);  //  8.39 MB
    unsigned short* Vt   = (unsigned short*)(ws + 114884608);  //  8.39 MB
    int*            fcnt = (int*)          (ws + 123273216);   // 64 B
    int*            flst = (int*)          (ws + 123273280);   // 256 KB

    setup_kernel  <<<512, 256, 0, stream>>>(ct, st, km64, fcnt);
    ksum_kernel   <<<dim3(32, 16), 256, 0, stream>>>(hs, ct, st, Act, Ast);
    kmeanw_kernel <<<256, 256, 0, stream>>>(Act, Ast, wk, km64);
    split_kernel  <<<8192, 256, 0, stream>>>(hs, hsh, 2097152);
    packall_kernel<<<10240, 256, 0, stream>>>(wq, wk, wv, wo, Wth, woth);
    gemm_kernel   <<<dim3(24, 32), 256, 0, stream>>>(hsh, Wth, Cqkv, 4096, 3072, 2048);
    ropegate_kernel<<<4096, 256, 0, stream>>>(Cqkv, ct, st, km64, mskb, fcnt, flst);
    repair_kernel <<<2048, 256, 0, stream>>>(hs, wq, ct, st, km64, fcnt, flst, mskb);
    kvprep_kernel <<<256, 256, 0, stream>>>(Cqkv, Kh, Vt);
    attn_kernel   <<<1024, 256, 0, stream>>>(Cqkv, Kh, Vt, mskb, Og);
    gemm_kernel   <<<dim3(16, 32), 256, 0, stream>>>(Og, woth, out, 4096, 2048, 2048);
}